// Round 7
// baseline (218.475 us; speedup 1.0000x reference)
//
#include <hip/hip_runtime.h>
#include <hip/hip_bf16.h>

#define V_ 32000
#define E_ 100
#define H_ 128
#define B_ 1024
#define T_ 256

typedef float f32x4 __attribute__((ext_vector_type(4)));
typedef int   i32x4 __attribute__((ext_vector_type(4)));
typedef __bf16 bf16x8 __attribute__((ext_vector_type(8)));
typedef __bf16 bf16x4 __attribute__((ext_vector_type(4)));

__device__ __forceinline__ f32x4 mfma16(bf16x8 a, bf16x8 b, f32x4 c) {
    return __builtin_amdgcn_mfma_f32_16x16x32_bf16(a, b, c, 0, 0, 0);
}

// Granule layout (per 128x128 matrix): granule g holds elements
// [row = (g>>8)*16 + (g&15)][k = ((g>>4)&15)*8 .. +8), stored at elems g*8.
// MFMA frag read for (tile,kc) at lane l: elem off tile*2048 + kc*512 + l*8.

// ---------------------------------------------------------------------------
// K0a: embb[v][k] = bf16(emb[v][k]) zero-padded K 100->128.  grid 4000x256.
// ---------------------------------------------------------------------------
__global__ void k0_emb(const float* __restrict__ emb, __bf16* __restrict__ embb) {
    int i = blockIdx.x * 256 + threadIdx.x;      // one bf16x4 per thread
    int e4 = i * 4;
    int v = e4 >> 7, k = e4 & 127;
    if (v >= V_) return;
    bf16x4 o;
    if (k < E_) {
        f32x4 p = *(const f32x4*)&emb[(size_t)v * E_ + k];
#pragma unroll
        for (int r = 0; r < 4; ++r) o[r] = (__bf16)p[r];
    } else {
#pragma unroll
        for (int r = 0; r < 4; ++r) o[r] = (__bf16)0.0f;
    }
    *(bf16x4*)&embb[(size_t)v * 128 + k] = o;
}

// ---------------------------------------------------------------------------
// K0b: W_ih (128x100 f32) -> granule-layout bf16 (K padded to 128). 1 block.
// ---------------------------------------------------------------------------
__global__ void k0_wih(const float* __restrict__ Wih, __bf16* __restrict__ wihb) {
    int tid = threadIdx.x;
#pragma unroll
    for (int i = 0; i < 4; ++i) {
        int t2 = tid + i * 512;
        int tile = t2 >> 8, row4 = (t2 >> 4) & 15, ch = t2 & 15;
        int grow = tile * 16 + row4;
        int g = tile * 256 + ch * 16 + row4;
        bf16x8 o;
#pragma unroll
        for (int e = 0; e < 8; ++e) {
            int k = ch * 8 + e;
            o[e] = (k < E_) ? (__bf16)Wih[(size_t)grow * E_ + k] : (__bf16)0.0f;
        }
        *(bf16x8*)&wihb[(size_t)g * 8] = o;
    }
}

// ---------------------------------------------------------------------------
// K0c: W_fc (32000x128 f32) -> 250 x granule-layout bf16. grid 250x512.
// ---------------------------------------------------------------------------
__global__ void k0_wfc(const float* __restrict__ Wfc, __bf16* __restrict__ wfcb) {
    int gv = blockIdx.x, tid = threadIdx.x;
#pragma unroll
    for (int i = 0; i < 4; ++i) {
        int t2 = tid + i * 512;
        int tile = t2 >> 8, row4 = (t2 >> 4) & 15, ch = t2 & 15;
        int grow = gv * 128 + tile * 16 + row4;
        int g = tile * 256 + ch * 16 + row4;
        const float* src = Wfc + (size_t)grow * H_ + ch * 8;
        f32x4 p0 = *(const f32x4*)src, p1 = *(const f32x4*)(src + 4);
        bf16x8 o;
#pragma unroll
        for (int e = 0; e < 4; ++e) {
            o[e] = (__bf16)p0[e];
            o[4 + e] = (__bf16)p1[e];
        }
        *(bf16x8*)&wfcb[(size_t)gv * 16384 + g * 8] = o;
    }
}

// ---------------------------------------------------------------------------
// K1: xpb[t][b][h] = bf16(emb[x[b,t]] @ W_ih^T + b_ih + b_hh). LDS-free.
// 8 waves = 4 n-tiles x 2 m-halves (B-gather dup 2x, was 4x). Wave holds its
// m-half of W_ih (16 frags, 64 VGPR) for 4 timesteps; x loaded as int4.
// grid (B/64 = 16, T/4 = 64), 512 thr.
// ---------------------------------------------------------------------------
__global__ __launch_bounds__(512, 1) void k1_xproj(
    const int* __restrict__ x, const __bf16* __restrict__ embb,
    const __bf16* __restrict__ wihb, const float* __restrict__ bih,
    const float* __restrict__ bhh, __bf16* __restrict__ xpb)
{
    const int tid = threadIdx.x;
    const int lane = tid & 63, w = tid >> 6;
    const int nt = w >> 1;               // n-tile 0..3
    const int mh = w & 1;                // m-half 0..1 (4 m-tiles each)
    const int b0 = blockIdx.x * 64;
    const int t0 = blockIdx.y * 4;
    const int sub = lane >> 4, rc = lane & 15;

    bf16x8 af[4][4];
#pragma unroll
    for (int m = 0; m < 4; ++m)
#pragma unroll
        for (int kc = 0; kc < 4; ++kc)
            af[m][kc] = *(const bf16x8*)&wihb[(size_t)(((mh * 4 + m) * 256) + kc * 64 + lane) * 8];

    f32x4 bias4[4];
#pragma unroll
    for (int m = 0; m < 4; ++m) {
        int h0 = (mh * 4 + m) * 16 + sub * 4;
        bias4[m] = *(const f32x4*)&bih[h0] + *(const f32x4*)&bhh[h0];
    }

    i32x4 xr4 = *(const i32x4*)&x[(size_t)(b0 + nt * 16 + rc) * T_ + t0];

#pragma unroll
    for (int tt = 0; tt < 4; ++tt) {
        int xv = xr4[tt];
        bf16x8 bf[4];
#pragma unroll
        for (int kc = 0; kc < 4; ++kc)
            bf[kc] = *(const bf16x8*)&embb[(size_t)xv * 128 + (kc * 4 + sub) * 8];

        f32x4 acc[4];
#pragma unroll
        for (int m = 0; m < 4; ++m) acc[m] = (f32x4){0.f, 0.f, 0.f, 0.f};
#pragma unroll
        for (int kc = 0; kc < 4; ++kc)
#pragma unroll
            for (int m = 0; m < 4; ++m)
                acc[m] = mfma16(af[m][kc], bf[kc], acc[m]);

#pragma unroll
        for (int m = 0; m < 4; ++m) {
            f32x4 v = acc[m] + bias4[m];
            bf16x4 o;
#pragma unroll
            for (int r = 0; r < 4; ++r) o[r] = (__bf16)v[r];
            __bf16* dst = xpb + ((size_t)(t0 + tt) * B_ + b0 + nt * 16 + rc) * H_
                              + (mh * 4 + m) * 16 + sub * 4;
            *(bf16x4*)dst = o;
        }
    }
}

// ---------------------------------------------------------------------------
// K2: RNN scan. 64 blocks x 16 batch; 4 waves (1/SIMD); wave w owns hidden
// rows [32w, 32w+32) as two 16-row tiles. Halves LDS h-traffic vs 8-wave.
// W_hh bf16 in regs; h in conflict-free granule LDS; xt folded into MFMA
// C-init; 4 chains of depth 2; 2x ds_write_b64 (dense); 1 barrier/step.
// ---------------------------------------------------------------------------
__global__ __launch_bounds__(256, 1) void k2_rnn(
    const __bf16* __restrict__ xpb, const float* __restrict__ Whh,
    __bf16* __restrict__ hg)
{
    __shared__ __align__(16) __bf16 Hg[2][2048];
    const int tid = threadIdx.x;
    const int lane = tid & 63, w = tid >> 6;      // w: 0..3
    const int bi = blockIdx.x;
    const int b0 = bi * 16;
    const int sub = lane >> 4, c = lane & 15;

    // A fragments: W_hh rows w*32 + m*16 + c; loop-invariant
    bf16x8 wah[2][4];
#pragma unroll
    for (int m = 0; m < 2; ++m)
#pragma unroll
        for (int kc = 0; kc < 4; ++kc) {
            const float* src = Whh + (size_t)(w * 32 + m * 16 + c) * H_ + kc * 32 + sub * 8;
            f32x4 p0 = *(const f32x4*)src, p1 = *(const f32x4*)(src + 4);
            bf16x8 h8;
#pragma unroll
            for (int e = 0; e < 4; ++e) {
                h8[e] = (__bf16)p0[e];
                h8[4 + e] = (__bf16)p1[e];
            }
            wah[m][kc] = h8;
        }

    {
        bf16x8 z8;
#pragma unroll
        for (int e = 0; e < 8; ++e) z8[e] = (__bf16)0.0f;
        *(bf16x8*)&Hg[0][tid * 8] = z8;           // 256 thr x 8 = 2048
    }
    __syncthreads();

    // xt bases for m=0,1: rows of this lane's outputs, batch col c
    const __bf16* xb = xpb + (size_t)(b0 + c) * H_ + w * 32 + sub * 4;
    const size_t xstep = (size_t)B_ * H_;
    bf16x4 xr0[2], xr1[2], xr2[2], xr3[2];
#pragma unroll
    for (int m = 0; m < 2; ++m) {
        xr0[m] = *(const bf16x4*)(xb + m * 16);
        xr1[m] = *(const bf16x4*)(xb + xstep + m * 16);
        xr2[m] = *(const bf16x4*)(xb + 2 * xstep + m * 16);
    }

    // LDS write elem-offsets for m=0,1 (granule layout, dense 512B/wave)
    int wbo[2];
#pragma unroll
    for (int m = 0; m < 2; ++m)
        wbo[m] = (w * 64 + (2 * m + (sub >> 1)) * 16 + c) * 8 + (sub & 1) * 4;

    int p = 0;
    for (int tq = 0; tq < T_; ++tq) {
        size_t tn = (tq + 3 < T_) ? (size_t)(tq + 3) : (size_t)(T_ - 1);
#pragma unroll
        for (int m = 0; m < 2; ++m)
            xr3[m] = *(const bf16x4*)(xb + tn * xstep + m * 16);

        const __bf16* Hp = &Hg[p][0];
        bf16x8 hb0 = *(const bf16x8*)(Hp + 0 * 512 + lane * 8);
        bf16x8 hb1 = *(const bf16x8*)(Hp + 1 * 512 + lane * 8);
        bf16x8 hb2 = *(const bf16x8*)(Hp + 2 * 512 + lane * 8);
        bf16x8 hb3 = *(const bf16x8*)(Hp + 3 * 512 + lane * 8);

        // C-init with xt (in regs for 3 steps already)
        f32x4 x0, x1;
#pragma unroll
        for (int r = 0; r < 4; ++r) {
            x0[r] = (float)xr0[0][r];
            x1[r] = (float)xr0[1][r];
        }
        f32x4 zz = {0.f, 0.f, 0.f, 0.f};
        f32x4 a00 = mfma16(wah[0][0], hb0, x0);
        f32x4 a01 = mfma16(wah[0][1], hb1, zz);
        f32x4 a10 = mfma16(wah[1][0], hb0, x1);
        f32x4 a11 = mfma16(wah[1][1], hb1, zz);
        a00 = mfma16(wah[0][2], hb2, a00);
        a01 = mfma16(wah[0][3], hb3, a01);
        a10 = mfma16(wah[1][2], hb2, a10);
        a11 = mfma16(wah[1][3], hb3, a11);

        __bf16* Hw = &Hg[p ^ 1][0];
#pragma unroll
        for (int m = 0; m < 2; ++m) {
            f32x4 s = (m == 0) ? (a00 + a01) : (a10 + a11);
            bf16x4 h4;
#pragma unroll
            for (int r = 0; r < 4; ++r) {
                float e;
                asm("v_exp_f32 %0, %1" : "=v"(e) : "v"(s[r] * 2.8853900817779268f));
                float ep1 = e + 1.0f;
                float rcp;
                asm("v_rcp_f32 %0, %1" : "=v"(rcp) : "v"(ep1));
                float h = 1.0f - 2.0f * rcp;
                h4[r] = (__bf16)h;
            }
            if (tq == T_ - 1)
                *(bf16x4*)&hg[(size_t)(bi >> 3) * 16384
                              + ((size_t)(bi & 7) * 256 + wbo[m] / 8) * 8 + (wbo[m] & 7)] = h4;
            *(bf16x4*)&Hw[wbo[m]] = h4;
        }

        asm volatile("s_waitcnt lgkmcnt(0)" ::: "memory");
        __builtin_amdgcn_s_barrier();
        __builtin_amdgcn_sched_barrier(0);
        p ^= 1;
#pragma unroll
        for (int m = 0; m < 2; ++m) {
            xr0[m] = xr1[m]; xr1[m] = xr2[m]; xr2[m] = xr3[m];
        }
    }
}

// ---------------------------------------------------------------------------
// K3: out[b][v] = h[b] @ W_fc[v]^T + b_fc[v]. One block per v-tile (gv);
// A-frags (wfcb) loaded ONCE, loop over all 8 batch-tiles. grid 250, 512 thr.
// ---------------------------------------------------------------------------
__global__ __launch_bounds__(512, 1) void k3_head(
    const __bf16* __restrict__ wfcb, const float* __restrict__ Wfc,
    const __bf16* __restrict__ hg, const float* __restrict__ bfc,
    float* __restrict__ out)
{
    const int tid = threadIdx.x;
    const int lane = tid & 63, w = tid >> 6;
    const int gv = blockIdx.x;
    const int v0 = gv * 128;
    const int sub = lane >> 4, rc = lane & 15;
    const int mt0 = (w & 3) * 2, nt0 = (w >> 2) * 4;

    bf16x8 af[2][4];
    if (wfcb != nullptr) {
#pragma unroll
        for (int m = 0; m < 2; ++m)
#pragma unroll
            for (int kc = 0; kc < 4; ++kc)
                af[m][kc] = *(const bf16x8*)&wfcb[(size_t)gv * 16384
                              + (size_t)(((mt0 + m) * 256) + kc * 64 + lane) * 8];
    } else {
#pragma unroll
        for (int m = 0; m < 2; ++m)
#pragma unroll
            for (int kc = 0; kc < 4; ++kc) {
                int row = v0 + (mt0 + m) * 16 + rc;
                const float* src = Wfc + (size_t)row * H_ + (kc * 4 + sub) * 8;
                f32x4 p0 = *(const f32x4*)src, p1 = *(const f32x4*)(src + 4);
                bf16x8 h8;
#pragma unroll
                for (int e = 0; e < 4; ++e) {
                    h8[e] = (__bf16)p0[e];
                    h8[4 + e] = (__bf16)p1[e];
                }
                af[m][kc] = h8;
            }
    }

    f32x4 bias4[2];
#pragma unroll
    for (int m = 0; m < 2; ++m)
        bias4[m] = *(const f32x4*)&bfc[v0 + (mt0 + m) * 16 + sub * 4];

    for (int bt = 0; bt < 8; ++bt) {
        const int b0 = bt * 128;
        f32x4 acc[2][4];
#pragma unroll
        for (int m = 0; m < 2; ++m)
#pragma unroll
            for (int n = 0; n < 4; ++n) acc[m][n] = (f32x4){0.f, 0.f, 0.f, 0.f};

#pragma unroll
        for (int kc = 0; kc < 4; ++kc) {
            bf16x8 bf[4];
#pragma unroll
            for (int n = 0; n < 4; ++n)
                bf[n] = *(const bf16x8*)&hg[(size_t)bt * 16384
                          + (size_t)(((nt0 + n) * 256) + kc * 64 + lane) * 8];
#pragma unroll
            for (int n = 0; n < 4; ++n)
#pragma unroll
                for (int m = 0; m < 2; ++m)
                    acc[m][n] = mfma16(af[m][kc], bf[n], acc[m][n]);
        }
#pragma unroll
        for (int n = 0; n < 4; ++n)
#pragma unroll
            for (int m = 0; m < 2; ++m) {
                f32x4 v = acc[m][n] + bias4[m];
                float* dst = out + (size_t)(b0 + (nt0 + n) * 16 + rc) * V_
                                 + v0 + (mt0 + m) * 16 + sub * 4;
                *(f32x4*)dst = v;
            }
    }
}

extern "C" void kernel_launch(void* const* d_in, const int* in_sizes, int n_in,
                              void* d_out, int out_size, void* d_ws, size_t ws_size,
                              hipStream_t stream) {
    const int*   x   = (const int*)d_in[0];
    const float* emb = (const float*)d_in[1];
    const float* Wih = (const float*)d_in[2];
    const float* Whh = (const float*)d_in[3];
    const float* bih = (const float*)d_in[4];
    const float* bhh = (const float*)d_in[5];
    const float* Wfc = (const float*)d_in[6];
    const float* bfc = (const float*)d_in[7];
    float* out = (float*)d_out;

    const size_t SZ_HG   = 262144;      // 8 x 16384 bf16
    const size_t SZ_WIHB = 32768;
    const size_t SZ_EMBB = (size_t)V_ * 128 * 2;        // 8.192 MB
    const size_t SZ_WFCB = (size_t)V_ * 128 * 2;        // 8.192 MB
    const size_t SZ_XPB  = (size_t)T_ * B_ * H_ * 2;    // 64 MB

    char* wsb = (char*)d_ws;
    size_t off = 0;
    auto take = [&](size_t n) -> char* {
        char* p = wsb + off;
        off += (n + 255) & ~(size_t)255;
        return p;
    };
    char* outb = (char*)d_out;
    size_t ooff = 0;
    auto takeOut = [&](size_t n) -> char* {
        char* p = outb + ooff;
        ooff += (n + 255) & ~(size_t)255;
        return p;
    };
    auto fits = [&](size_t n) { return off + n + 256 <= ws_size; };

    __bf16* hgp   = (__bf16*)take(SZ_HG);     // required in ws
    __bf16* wihb  = (__bf16*)take(SZ_WIHB);   // required in ws
    __bf16* wfcb  = nullptr;                  // must be in ws (K3 reads during out write)
    if (fits(SZ_WFCB)) wfcb = (__bf16*)take(SZ_WFCB);
    __bf16* embb  = fits(SZ_EMBB) ? (__bf16*)take(SZ_EMBB) : (__bf16*)takeOut(SZ_EMBB);
    __bf16* xpb   = fits(SZ_XPB)  ? (__bf16*)take(SZ_XPB)  : (__bf16*)takeOut(SZ_XPB);

    k0_emb<<<4000, 256, 0, stream>>>(emb, embb);
    k0_wih<<<1, 512, 0, stream>>>(Wih, wihb);
    if (wfcb) k0_wfc<<<250, 512, 0, stream>>>(Wfc, wfcb);

    k1_xproj<<<dim3(16, 64), 512, 0, stream>>>(x, embb, wihb, bih, bhh, xpb);
    k2_rnn<<<dim3(64), 256, 0, stream>>>(xpb, Whh, hgp);
    k3_head<<<dim3(250), 512, 0, stream>>>(wfcb, Wfc, hgp, bfc, out);
}

// Round 8
// 165.537 us; speedup vs baseline: 1.3198x; 1.3198x over previous
//
#include <hip/hip_runtime.h>
#include <hip/hip_bf16.h>

#define V_ 32000
#define E_ 100
#define H_ 128
#define B_ 1024
#define T_ 256

typedef float f32x4 __attribute__((ext_vector_type(4)));
typedef int   i32x4 __attribute__((ext_vector_type(4)));
typedef __bf16 bf16x8 __attribute__((ext_vector_type(8)));
typedef __bf16 bf16x4 __attribute__((ext_vector_type(4)));

__device__ __forceinline__ f32x4 mfma16(bf16x8 a, bf16x8 b, f32x4 c) {
    return __builtin_amdgcn_mfma_f32_16x16x32_bf16(a, b, c, 0, 0, 0);
}

// Granule layout (per 128x128 matrix): granule g holds elements
// [row = (g>>8)*16 + (g&15)][k = ((g>>4)&15)*8 .. +8), stored at elems g*8.
// MFMA frag read for (tile,kc) at lane l: elem off tile*2048 + kc*512 + l*8.

// ---------------------------------------------------------------------------
// K0a: embb[v][k] = bf16(emb[v][k]) zero-padded K 100->128.  grid 4000x256.
// ---------------------------------------------------------------------------
__global__ void k0_emb(const float* __restrict__ emb, __bf16* __restrict__ embb) {
    int i = blockIdx.x * 256 + threadIdx.x;      // one bf16x4 per thread
    int e4 = i * 4;
    int v = e4 >> 7, k = e4 & 127;
    if (v >= V_) return;
    bf16x4 o;
    if (k < E_) {
        f32x4 p = *(const f32x4*)&emb[(size_t)v * E_ + k];
#pragma unroll
        for (int r = 0; r < 4; ++r) o[r] = (__bf16)p[r];
    } else {
#pragma unroll
        for (int r = 0; r < 4; ++r) o[r] = (__bf16)0.0f;
    }
    *(bf16x4*)&embb[(size_t)v * 128 + k] = o;
}

// ---------------------------------------------------------------------------
// K0b: W_ih (128x100 f32) -> granule-layout bf16 (K padded to 128). 1 block.
// ---------------------------------------------------------------------------
__global__ void k0_wih(const float* __restrict__ Wih, __bf16* __restrict__ wihb) {
    int tid = threadIdx.x;
#pragma unroll
    for (int i = 0; i < 4; ++i) {
        int t2 = tid + i * 512;
        int tile = t2 >> 8, row4 = (t2 >> 4) & 15, ch = t2 & 15;
        int grow = tile * 16 + row4;
        int g = tile * 256 + ch * 16 + row4;
        bf16x8 o;
#pragma unroll
        for (int e = 0; e < 8; ++e) {
            int k = ch * 8 + e;
            o[e] = (k < E_) ? (__bf16)Wih[(size_t)grow * E_ + k] : (__bf16)0.0f;
        }
        *(bf16x8*)&wihb[(size_t)g * 8] = o;
    }
}

// ---------------------------------------------------------------------------
// K1: xpb[t][b][h] = bf16(emb[x[b,t]] @ W_ih^T + b_ih + b_hh). LDS-free.
// 8 waves = 4 n-tiles x 2 m-halves. Wave holds its m-half of W_ih in regs
// for 4 timesteps; x loaded as int4. grid (B/64 = 16, T/4 = 64), 512 thr.
// ---------------------------------------------------------------------------
__global__ __launch_bounds__(512, 1) void k1_xproj(
    const int* __restrict__ x, const __bf16* __restrict__ embb,
    const __bf16* __restrict__ wihb, const float* __restrict__ bih,
    const float* __restrict__ bhh, __bf16* __restrict__ xpb)
{
    const int tid = threadIdx.x;
    const int lane = tid & 63, w = tid >> 6;
    const int nt = w >> 1;               // n-tile 0..3
    const int mh = w & 1;                // m-half 0..1 (4 m-tiles each)
    const int b0 = blockIdx.x * 64;
    const int t0 = blockIdx.y * 4;
    const int sub = lane >> 4, rc = lane & 15;

    bf16x8 af[4][4];
#pragma unroll
    for (int m = 0; m < 4; ++m)
#pragma unroll
        for (int kc = 0; kc < 4; ++kc)
            af[m][kc] = *(const bf16x8*)&wihb[(size_t)(((mh * 4 + m) * 256) + kc * 64 + lane) * 8];

    f32x4 bias4[4];
#pragma unroll
    for (int m = 0; m < 4; ++m) {
        int h0 = (mh * 4 + m) * 16 + sub * 4;
        bias4[m] = *(const f32x4*)&bih[h0] + *(const f32x4*)&bhh[h0];
    }

    i32x4 xr4 = *(const i32x4*)&x[(size_t)(b0 + nt * 16 + rc) * T_ + t0];

#pragma unroll
    for (int tt = 0; tt < 4; ++tt) {
        int xv = xr4[tt];
        bf16x8 bf[4];
#pragma unroll
        for (int kc = 0; kc < 4; ++kc)
            bf[kc] = *(const bf16x8*)&embb[(size_t)xv * 128 + (kc * 4 + sub) * 8];

        f32x4 acc[4];
#pragma unroll
        for (int m = 0; m < 4; ++m) acc[m] = (f32x4){0.f, 0.f, 0.f, 0.f};
#pragma unroll
        for (int kc = 0; kc < 4; ++kc)
#pragma unroll
            for (int m = 0; m < 4; ++m)
                acc[m] = mfma16(af[m][kc], bf[kc], acc[m]);

#pragma unroll
        for (int m = 0; m < 4; ++m) {
            f32x4 v = acc[m] + bias4[m];
            bf16x4 o;
#pragma unroll
            for (int r = 0; r < 4; ++r) o[r] = (__bf16)v[r];
            __bf16* dst = xpb + ((size_t)(t0 + tt) * B_ + b0 + nt * 16 + rc) * H_
                              + (mh * 4 + m) * 16 + sub * 4;
            *(bf16x4*)dst = o;
        }
    }
}

// ---------------------------------------------------------------------------
// K2: RNN scan. 64 blocks x 16 batch; 8 waves (2/SIMD); wave w owns hidden
// rows [16w,16w+16). Time loop unrolled x4 with position-named prefetch regs
// (no register rotation -> compiler emits counted vmcnt, loads stay in flight
// across barriers). Static LDS ping-pong; xt folded into MFMA C-init; hg
// store hoisted out of loop. 1 barrier/step.
// ---------------------------------------------------------------------------
__global__ __launch_bounds__(512, 1) void k2_rnn(
    const __bf16* __restrict__ xpb, const float* __restrict__ Whh,
    __bf16* __restrict__ hg)
{
    __shared__ __align__(16) __bf16 Hg[2][2048];
    const int tid = threadIdx.x;
    const int lane = tid & 63, w = tid >> 6;
    const int bi = blockIdx.x;
    const int b0 = bi * 16;
    const int sub = lane >> 4, c = lane & 15;

    // A fragments: W_hh rows w*16 + c (bf16); loop-invariant
    bf16x8 wah[4];
#pragma unroll
    for (int kc = 0; kc < 4; ++kc) {
        const float* src = Whh + (size_t)(w * 16 + c) * H_ + kc * 32 + sub * 8;
        f32x4 p0 = *(const f32x4*)src, p1 = *(const f32x4*)(src + 4);
        bf16x8 h8;
#pragma unroll
        for (int e = 0; e < 4; ++e) {
            h8[e] = (__bf16)p0[e];
            h8[4 + e] = (__bf16)p1[e];
        }
        wah[kc] = h8;
    }

    if (tid < 256) {
        bf16x8 z8;
#pragma unroll
        for (int e = 0; e < 8; ++e) z8[e] = (__bf16)0.0f;
        *(bf16x8*)&Hg[0][tid * 8] = z8;
    }
    __syncthreads();

    const int i0 = w * 16 + sub * 4;            // this lane's 4 hidden-out rows
    const __bf16* xq = xpb + (size_t)(b0 + c) * H_ + i0;
    const size_t xstep = (size_t)B_ * H_;

    // LDS write elem-offset for hidden rows i0..i0+3, col c (granule layout)
    const int wb = (((w >> 1) * 64 + ((w & 1) * 2 + (sub >> 1)) * 16 + c) << 3)
                 + (sub & 1) * 4;

    bf16x4 h4;                                   // last-written h (for hg)

#define K2_STEP(PK, XREG) do {                                              \
        const __bf16* Hp = &Hg[PK][0];                                      \
        bf16x8 hb0 = *(const bf16x8*)(Hp + lane * 8);                       \
        bf16x8 hb1 = *(const bf16x8*)(Hp + 512 + lane * 8);                 \
        bf16x8 hb2 = *(const bf16x8*)(Hp + 1024 + lane * 8);                \
        bf16x8 hb3 = *(const bf16x8*)(Hp + 1536 + lane * 8);                \
        f32x4 xf;                                                           \
        _Pragma("unroll")                                                   \
        for (int r = 0; r < 4; ++r) xf[r] = (float)XREG[r];                 \
        f32x4 zz = {0.f, 0.f, 0.f, 0.f};                                    \
        f32x4 a0 = mfma16(wah[0], hb0, xf);                                 \
        f32x4 a1 = mfma16(wah[1], hb1, zz);                                 \
        a0 = mfma16(wah[2], hb2, a0);                                       \
        a1 = mfma16(wah[3], hb3, a1);                                       \
        f32x4 s = a0 + a1;                                                  \
        _Pragma("unroll")                                                   \
        for (int r = 0; r < 4; ++r) {                                       \
            float e;                                                        \
            asm("v_exp_f32 %0, %1" : "=v"(e) : "v"(s[r] * 2.8853900817779268f)); \
            float ep1 = e + 1.0f;                                           \
            float rcp;                                                      \
            asm("v_rcp_f32 %0, %1" : "=v"(rcp) : "v"(ep1));                 \
            h4[r] = (__bf16)(1.0f - 2.0f * rcp);                            \
        }                                                                   \
        *(bf16x4*)&Hg[(PK) ^ 1][wb] = h4;                                   \
        asm volatile("s_waitcnt lgkmcnt(0)" ::: "memory");                  \
        __builtin_amdgcn_s_barrier();                                       \
        __builtin_amdgcn_sched_barrier(0);                                  \
    } while (0)

    // steps 0..3 prefetch (position-named, no rotation)
    bf16x4 xc0 = *(const bf16x4*)(xq);
    bf16x4 xc1 = *(const bf16x4*)(xq + xstep);
    bf16x4 xc2 = *(const bf16x4*)(xq + 2 * xstep);
    bf16x4 xc3 = *(const bf16x4*)(xq + 3 * xstep);
    xq += 4 * xstep;

    for (int j = 0; j < T_ / 4; ++j) {
        bf16x4 xn0, xn1, xn2, xn3;
        if (j < T_ / 4 - 1) {
            xn0 = *(const bf16x4*)(xq);
            xn1 = *(const bf16x4*)(xq + xstep);
            xn2 = *(const bf16x4*)(xq + 2 * xstep);
            xn3 = *(const bf16x4*)(xq + 3 * xstep);
            xq += 4 * xstep;
        }
        K2_STEP(0, xc0);
        K2_STEP(1, xc1);
        K2_STEP(0, xc2);
        K2_STEP(1, xc3);
        xc0 = xn0; xc1 = xn1; xc2 = xn2; xc3 = xn3;
    }
#undef K2_STEP

    // final h of step T-1 (written to Hg[0]) -> hg granules for K3
    hg[0] = hg[0];  // no-op keep-alive (compiler barrier not needed; direct store below)
    *(bf16x4*)&hg[(size_t)(bi >> 3) * 16384 + (size_t)(bi & 7) * 2048 + wb] = h4;
}

// ---------------------------------------------------------------------------
// K3: out[b][v] = h[b] @ W_fc[v]^T + b_fc[v]. One block per v-tile (gv);
// A-frags cvt'd from f32 Wfc ONCE (each value read exactly once globally ->
// no pre-pass), loop over all 8 batch-tiles. grid 250, 512 thr.
// ---------------------------------------------------------------------------
__global__ __launch_bounds__(512, 1) void k3_head(
    const float* __restrict__ Wfc, const __bf16* __restrict__ hg,
    const float* __restrict__ bfc, float* __restrict__ out)
{
    const int tid = threadIdx.x;
    const int lane = tid & 63, w = tid >> 6;
    const int gv = blockIdx.x;
    const int v0 = gv * 128;
    const int sub = lane >> 4, rc = lane & 15;
    const int mt0 = (w & 3) * 2, nt0 = (w >> 2) * 4;

    bf16x8 af[2][4];
#pragma unroll
    for (int m = 0; m < 2; ++m)
#pragma unroll
        for (int kc = 0; kc < 4; ++kc) {
            int row = v0 + (mt0 + m) * 16 + rc;
            const float* src = Wfc + (size_t)row * H_ + (kc * 4 + sub) * 8;
            f32x4 p0 = *(const f32x4*)src, p1 = *(const f32x4*)(src + 4);
            bf16x8 h8;
#pragma unroll
            for (int e = 0; e < 4; ++e) {
                h8[e] = (__bf16)p0[e];
                h8[4 + e] = (__bf16)p1[e];
            }
            af[m][kc] = h8;
        }

    f32x4 bias4[2];
#pragma unroll
    for (int m = 0; m < 2; ++m)
        bias4[m] = *(const f32x4*)&bfc[v0 + (mt0 + m) * 16 + sub * 4];

    for (int bt = 0; bt < 8; ++bt) {
        const int b0 = bt * 128;
        f32x4 acc[2][4];
#pragma unroll
        for (int m = 0; m < 2; ++m)
#pragma unroll
            for (int n = 0; n < 4; ++n) acc[m][n] = (f32x4){0.f, 0.f, 0.f, 0.f};

#pragma unroll
        for (int kc = 0; kc < 4; ++kc) {
            bf16x8 bf[4];
#pragma unroll
            for (int n = 0; n < 4; ++n)
                bf[n] = *(const bf16x8*)&hg[(size_t)bt * 16384
                          + (size_t)(((nt0 + n) * 256) + kc * 64 + lane) * 8];
#pragma unroll
            for (int n = 0; n < 4; ++n)
#pragma unroll
                for (int m = 0; m < 2; ++m)
                    acc[m][n] = mfma16(af[m][kc], bf[n], acc[m][n]);
        }
#pragma unroll
        for (int n = 0; n < 4; ++n)
#pragma unroll
            for (int m = 0; m < 2; ++m) {
                f32x4 v = acc[m][n] + bias4[m];
                float* dst = out + (size_t)(b0 + (nt0 + n) * 16 + rc) * V_
                                 + v0 + (mt0 + m) * 16 + sub * 4;
                *(f32x4*)dst = v;
            }
    }
}

extern "C" void kernel_launch(void* const* d_in, const int* in_sizes, int n_in,
                              void* d_out, int out_size, void* d_ws, size_t ws_size,
                              hipStream_t stream) {
    const int*   x   = (const int*)d_in[0];
    const float* emb = (const float*)d_in[1];
    const float* Wih = (const float*)d_in[2];
    const float* Whh = (const float*)d_in[3];
    const float* bih = (const float*)d_in[4];
    const float* bhh = (const float*)d_in[5];
    const float* Wfc = (const float*)d_in[6];
    const float* bfc = (const float*)d_in[7];
    float* out = (float*)d_out;

    const size_t SZ_HG   = 262144;      // 8 x 16384 bf16
    const size_t SZ_WIHB = 32768;
    const size_t SZ_EMBB = (size_t)V_ * 128 * 2;        // 8.192 MB
    const size_t SZ_XPB  = (size_t)T_ * B_ * H_ * 2;    // 64 MB

    char* wsb = (char*)d_ws;
    size_t off = 0;
    auto take = [&](size_t n) -> char* {
        char* p = wsb + off;
        off += (n + 255) & ~(size_t)255;
        return p;
    };
    char* outb = (char*)d_out;
    size_t ooff = 0;
    auto takeOut = [&](size_t n) -> char* {
        char* p = outb + ooff;
        ooff += (n + 255) & ~(size_t)255;
        return p;
    };
    auto fits = [&](size_t n) { return off + n + 256 <= ws_size; };

    __bf16* hgp   = (__bf16*)take(SZ_HG);     // required in ws
    __bf16* wihb  = (__bf16*)take(SZ_WIHB);   // required in ws
    __bf16* embb  = fits(SZ_EMBB) ? (__bf16*)take(SZ_EMBB) : (__bf16*)takeOut(SZ_EMBB);
    __bf16* xpb   = fits(SZ_XPB)  ? (__bf16*)take(SZ_XPB)  : (__bf16*)takeOut(SZ_XPB);

    k0_emb<<<4000, 256, 0, stream>>>(emb, embb);
    k0_wih<<<1, 512, 0, stream>>>(Wih, wihb);

    k1_xproj<<<dim3(16, 64), 512, 0, stream>>>(x, embb, wihb, bih, bhh, xpb);
    k2_rnn<<<dim3(64), 512, 0, stream>>>(xpb, Whh, hgp);
    k3_head<<<dim3(250), 512, 0, stream>>>(Wfc, hgp, bfc, out);
}

// Round 9
// 151.728 us; speedup vs baseline: 1.4399x; 1.0910x over previous
//
#include <hip/hip_runtime.h>
#include <hip/hip_bf16.h>

#define V_ 32000
#define E_ 100
#define H_ 128
#define B_ 1024
#define T_ 256

typedef float f32x4 __attribute__((ext_vector_type(4)));
typedef int   i32x4 __attribute__((ext_vector_type(4)));
typedef __bf16 bf16x8 __attribute__((ext_vector_type(8)));
typedef __bf16 bf16x4 __attribute__((ext_vector_type(4)));

__device__ __forceinline__ f32x4 mfma16(bf16x8 a, bf16x8 b, f32x4 c) {
    return __builtin_amdgcn_mfma_f32_16x16x32_bf16(a, b, c, 0, 0, 0);
}

// ---------------------------------------------------------------------------
// K0: pp[v][h] = bf16( emb[v,:] @ W_ih^T + b_ih + b_hh )  (K = 100, f32 acc)
// The input projection depends only on vocab id -> precompute once for all
// 32000 ids; k2 then gathers pp rows directly (xp never materialized).
// Operand-swapped MFMA: A = W_ih (M=h), B = emb^T (col=vocab).
// grid 500 x 512thr; block covers 64 vocab; 8 waves = 4 v-tiles x 2 h-halves.
// ---------------------------------------------------------------------------
__global__ __launch_bounds__(512, 1) void k0_pp(
    const float* __restrict__ emb, const float* __restrict__ Wih,
    const float* __restrict__ bih, const float* __restrict__ bhh,
    __bf16* __restrict__ pp)
{
    const int tid = threadIdx.x;
    const int lane = tid & 63, w = tid >> 6;
    const int nt = w >> 1;               // vocab tile 0..3
    const int mh = w & 1;                // h half 0..1 (4 m-tiles each)
    const int v0 = blockIdx.x * 64;
    const int sub = lane >> 4, rc = lane & 15;
    const f32x4 z = {0.f, 0.f, 0.f, 0.f};

    // A-frags: W_ih[row = (mh*4+m)*16 + rc][k = kc*32 + sub*8 ..+8], K padded
    bf16x8 af[4][4];
#pragma unroll
    for (int m = 0; m < 4; ++m)
#pragma unroll
        for (int kc = 0; kc < 4; ++kc) {
            int row = (mh * 4 + m) * 16 + rc;
            int k0 = kc * 32 + sub * 8;
            const float* s = Wih + (size_t)row * E_ + k0;
            f32x4 p0 = (k0 + 4 <= E_) ? *(const f32x4*)s : z;
            f32x4 p1 = (k0 + 8 <= E_) ? *(const f32x4*)(s + 4) : z;
            bf16x8 h8;
#pragma unroll
            for (int e = 0; e < 4; ++e) {
                h8[e] = (__bf16)p0[e];
                h8[4 + e] = (__bf16)p1[e];
            }
            af[m][kc] = h8;
        }

    // B-frags: emb[vrow = v0 + nt*16 + rc][k], K padded
    bf16x8 bf[4];
#pragma unroll
    for (int kc = 0; kc < 4; ++kc) {
        int vrow = v0 + nt * 16 + rc;
        int k0 = kc * 32 + sub * 8;
        const float* s = emb + (size_t)vrow * E_ + k0;
        f32x4 p0 = (k0 + 4 <= E_) ? *(const f32x4*)s : z;
        f32x4 p1 = (k0 + 8 <= E_) ? *(const f32x4*)(s + 4) : z;
        bf16x8 h8;
#pragma unroll
        for (int e = 0; e < 4; ++e) {
            h8[e] = (__bf16)p0[e];
            h8[4 + e] = (__bf16)p1[e];
        }
        bf[kc] = h8;
    }

    f32x4 acc[4];
#pragma unroll
    for (int m = 0; m < 4; ++m) {
        int h0 = (mh * 4 + m) * 16 + sub * 4;
        acc[m] = *(const f32x4*)&bih[h0] + *(const f32x4*)&bhh[h0];
    }
#pragma unroll
    for (int kc = 0; kc < 4; ++kc)
#pragma unroll
        for (int m = 0; m < 4; ++m)
            acc[m] = mfma16(af[m][kc], bf[kc], acc[m]);

#pragma unroll
    for (int m = 0; m < 4; ++m) {
        int v = v0 + nt * 16 + rc;
        int h0 = (mh * 4 + m) * 16 + sub * 4;
        bf16x4 o;
#pragma unroll
        for (int r = 0; r < 4; ++r) o[r] = (__bf16)acc[m][r];
        *(bf16x4*)&pp[(size_t)v * H_ + h0] = o;
    }
}

// ---------------------------------------------------------------------------
// K2: RNN scan. 64 blocks x 16 batch; 8 waves (2/SIMD); wave w owns hidden
// rows [16w,16w+16). xt comes from pp[x[b,t]] gathers (L2/L3-resident 8MB
// table). Time loop unrolled x4 with position-named prefetch regs (counted
// vmcnt; gathers issued one 4-step group ahead, indices two groups ahead).
// Static LDS ping-pong; xt folded into MFMA C-init; 1 barrier/step.
// ---------------------------------------------------------------------------
__global__ __launch_bounds__(512, 1) void k2_rnn(
    const int* __restrict__ x, const __bf16* __restrict__ pp,
    const float* __restrict__ Whh, __bf16* __restrict__ hg)
{
    __shared__ __align__(16) __bf16 Hg[2][2048];
    const int tid = threadIdx.x;
    const int lane = tid & 63, w = tid >> 6;
    const int bi = blockIdx.x;
    const int b0 = bi * 16;
    const int sub = lane >> 4, c = lane & 15;

    // A fragments: W_hh rows w*16 + c (bf16); loop-invariant
    bf16x8 wah[4];
#pragma unroll
    for (int kc = 0; kc < 4; ++kc) {
        const float* src = Whh + (size_t)(w * 16 + c) * H_ + kc * 32 + sub * 8;
        f32x4 p0 = *(const f32x4*)src, p1 = *(const f32x4*)(src + 4);
        bf16x8 h8;
#pragma unroll
        for (int e = 0; e < 4; ++e) {
            h8[e] = (__bf16)p0[e];
            h8[4 + e] = (__bf16)p1[e];
        }
        wah[kc] = h8;
    }

    if (tid < 256) {
        bf16x8 z8;
#pragma unroll
        for (int e = 0; e < 8; ++e) z8[e] = (__bf16)0.0f;
        *(bf16x8*)&Hg[0][tid * 8] = z8;
    }
    __syncthreads();

    const int i0 = w * 16 + sub * 4;            // this lane's 4 hidden-out rows
    const int* xrow = x + (size_t)(b0 + c) * T_; // this lane's batch index row
    const __bf16* ppi = pp + i0;

    // LDS write elem-offset for hidden rows i0..i0+3, col c (granule layout)
    const int wb = (((w >> 1) * 64 + ((w & 1) * 2 + (sub >> 1)) * 16 + c) << 3)
                 + (sub & 1) * 4;

    bf16x4 h4;                                   // last-written h (for hg)

#define K2_STEP(PK, XREG) do {                                              \
        const __bf16* Hp = &Hg[PK][0];                                      \
        bf16x8 hb0 = *(const bf16x8*)(Hp + lane * 8);                       \
        bf16x8 hb1 = *(const bf16x8*)(Hp + 512 + lane * 8);                 \
        bf16x8 hb2 = *(const bf16x8*)(Hp + 1024 + lane * 8);                \
        bf16x8 hb3 = *(const bf16x8*)(Hp + 1536 + lane * 8);                \
        f32x4 xf;                                                           \
        _Pragma("unroll")                                                   \
        for (int r = 0; r < 4; ++r) xf[r] = (float)XREG[r];                 \
        f32x4 zz = {0.f, 0.f, 0.f, 0.f};                                    \
        f32x4 a0 = mfma16(wah[0], hb0, xf);                                 \
        f32x4 a1 = mfma16(wah[1], hb1, zz);                                 \
        a0 = mfma16(wah[2], hb2, a0);                                       \
        a1 = mfma16(wah[3], hb3, a1);                                       \
        f32x4 s = a0 + a1;                                                  \
        _Pragma("unroll")                                                   \
        for (int r = 0; r < 4; ++r) {                                       \
            float e;                                                        \
            asm("v_exp_f32 %0, %1" : "=v"(e) : "v"(s[r] * 2.8853900817779268f)); \
            float ep1 = e + 1.0f;                                           \
            float rcp;                                                      \
            asm("v_rcp_f32 %0, %1" : "=v"(rcp) : "v"(ep1));                 \
            h4[r] = (__bf16)(1.0f - 2.0f * rcp);                            \
        }                                                                   \
        *(bf16x4*)&Hg[(PK) ^ 1][wb] = h4;                                   \
        asm volatile("s_waitcnt lgkmcnt(0)" ::: "memory");                  \
        __builtin_amdgcn_s_barrier();                                       \
        __builtin_amdgcn_sched_barrier(0);                                  \
    } while (0)

    // prologue: indices for t0..3, gathers for steps 0..3, indices for t4..7
    i32x4 xsA = *(const i32x4*)(xrow);
    bf16x4 xc0 = *(const bf16x4*)(ppi + (size_t)xsA[0] * H_);
    bf16x4 xc1 = *(const bf16x4*)(ppi + (size_t)xsA[1] * H_);
    bf16x4 xc2 = *(const bf16x4*)(ppi + (size_t)xsA[2] * H_);
    bf16x4 xc3 = *(const bf16x4*)(ppi + (size_t)xsA[3] * H_);
    xsA = *(const i32x4*)(xrow + 4);

    for (int j = 0; j < T_ / 4; ++j) {
        bf16x4 xn0, xn1, xn2, xn3;
        i32x4 xsB = xsA;
        if (j < T_ / 4 - 1) {       // gathers for steps 4(j+1)..+3
            xn0 = *(const bf16x4*)(ppi + (size_t)xsA[0] * H_);
            xn1 = *(const bf16x4*)(ppi + (size_t)xsA[1] * H_);
            xn2 = *(const bf16x4*)(ppi + (size_t)xsA[2] * H_);
            xn3 = *(const bf16x4*)(ppi + (size_t)xsA[3] * H_);
        }
        if (j < T_ / 4 - 2)         // indices for steps 4(j+2)..+3
            xsB = *(const i32x4*)(xrow + 4 * (j + 2));
        K2_STEP(0, xc0);
        K2_STEP(1, xc1);
        K2_STEP(0, xc2);
        K2_STEP(1, xc3);
        xc0 = xn0; xc1 = xn1; xc2 = xn2; xc3 = xn3;
        xsA = xsB;
    }
#undef K2_STEP

    // final h of step T-1 -> hg granules for K3
    *(bf16x4*)&hg[(size_t)(bi >> 3) * 16384 + (size_t)(bi & 7) * 2048 + wb] = h4;
}

// ---------------------------------------------------------------------------
// K3: out[b][v] = h[b] @ W_fc[v]^T + b_fc[v]. One block per v-tile (gv);
// A-frags cvt'd from f32 Wfc ONCE (each value read exactly once globally),
// loop over all 8 batch-tiles. grid 250, 512 thr.
// ---------------------------------------------------------------------------
__global__ __launch_bounds__(512, 1) void k3_head(
    const float* __restrict__ Wfc, const __bf16* __restrict__ hg,
    const float* __restrict__ bfc, float* __restrict__ out)
{
    const int tid = threadIdx.x;
    const int lane = tid & 63, w = tid >> 6;
    const int gv = blockIdx.x;
    const int v0 = gv * 128;
    const int sub = lane >> 4, rc = lane & 15;
    const int mt0 = (w & 3) * 2, nt0 = (w >> 2) * 4;

    bf16x8 af[2][4];
#pragma unroll
    for (int m = 0; m < 2; ++m)
#pragma unroll
        for (int kc = 0; kc < 4; ++kc) {
            int row = v0 + (mt0 + m) * 16 + rc;
            const float* src = Wfc + (size_t)row * H_ + (kc * 4 + sub) * 8;
            f32x4 p0 = *(const f32x4*)src, p1 = *(const f32x4*)(src + 4);
            bf16x8 h8;
#pragma unroll
            for (int e = 0; e < 4; ++e) {
                h8[e] = (__bf16)p0[e];
                h8[4 + e] = (__bf16)p1[e];
            }
            af[m][kc] = h8;
        }

    f32x4 bias4[2];
#pragma unroll
    for (int m = 0; m < 2; ++m)
        bias4[m] = *(const f32x4*)&bfc[v0 + (mt0 + m) * 16 + sub * 4];

    for (int bt = 0; bt < 8; ++bt) {
        const int b0 = bt * 128;
        f32x4 acc[2][4];
#pragma unroll
        for (int m = 0; m < 2; ++m)
#pragma unroll
            for (int n = 0; n < 4; ++n) acc[m][n] = (f32x4){0.f, 0.f, 0.f, 0.f};

#pragma unroll
        for (int kc = 0; kc < 4; ++kc) {
            bf16x8 bf[4];
#pragma unroll
            for (int n = 0; n < 4; ++n)
                bf[n] = *(const bf16x8*)&hg[(size_t)bt * 16384
                          + (size_t)(((nt0 + n) * 256) + kc * 64 + lane) * 8];
#pragma unroll
            for (int n = 0; n < 4; ++n)
#pragma unroll
                for (int m = 0; m < 2; ++m)
                    acc[m][n] = mfma16(af[m][kc], bf[n], acc[m][n]);
        }
#pragma unroll
        for (int n = 0; n < 4; ++n)
#pragma unroll
            for (int m = 0; m < 2; ++m) {
                f32x4 v = acc[m][n] + bias4[m];
                float* dst = out + (size_t)(b0 + (nt0 + n) * 16 + rc) * V_
                                 + v0 + (mt0 + m) * 16 + sub * 4;
                *(f32x4*)dst = v;
            }
    }
}

extern "C" void kernel_launch(void* const* d_in, const int* in_sizes, int n_in,
                              void* d_out, int out_size, void* d_ws, size_t ws_size,
                              hipStream_t stream) {
    const int*   x   = (const int*)d_in[0];
    const float* emb = (const float*)d_in[1];
    const float* Wih = (const float*)d_in[2];
    const float* Whh = (const float*)d_in[3];
    const float* bih = (const float*)d_in[4];
    const float* bhh = (const float*)d_in[5];
    const float* Wfc = (const float*)d_in[6];
    const float* bfc = (const float*)d_in[7];
    float* out = (float*)d_out;

    const size_t SZ_HG = 262144;                    // 8 x 16384 bf16
    const size_t SZ_PP = (size_t)V_ * H_ * 2;       // 8.192 MB

    char* wsb = (char*)d_ws;
    size_t off = 0;
    auto take = [&](size_t n) -> char* {
        char* p = wsb + off;
        off += (n + 255) & ~(size_t)255;
        return p;
    };
    auto fits = [&](size_t n) { return off + n + 256 <= ws_size; };

    __bf16* hgp = (__bf16*)take(SZ_HG);             // required in ws
    // pp: prefer ws; fallback into d_out (k3 overwrites it only after k2 done)
    __bf16* pp = fits(SZ_PP) ? (__bf16*)take(SZ_PP) : (__bf16*)d_out;

    k0_pp<<<dim3(500), 512, 0, stream>>>(emb, Wih, bih, bhh, pp);
    k2_rnn<<<dim3(64), 512, 0, stream>>>(x, pp, Whh, hgp);
    k3_head<<<dim3(250), 512, 0, stream>>>(Wfc, hgp, bfc, out);
}

// Round 10
// 145.764 us; speedup vs baseline: 1.4988x; 1.0409x over previous
//
#include <hip/hip_runtime.h>
#include <hip/hip_bf16.h>

#define V_ 32000
#define E_ 100
#define H_ 128
#define B_ 1024
#define T_ 256

typedef float f32x4 __attribute__((ext_vector_type(4)));
typedef int   i32x4 __attribute__((ext_vector_type(4)));
typedef __bf16 bf16x8 __attribute__((ext_vector_type(8)));
typedef __bf16 bf16x4 __attribute__((ext_vector_type(4)));

__device__ __forceinline__ f32x4 mfma16(bf16x8 a, bf16x8 b, f32x4 c) {
    return __builtin_amdgcn_mfma_f32_16x16x32_bf16(a, b, c, 0, 0, 0);
}

// ---------------------------------------------------------------------------
// K0: pp[v][h] = bf16( emb[v,:] @ W_ih^T + b_ih + b_hh )  (K = 100, f32 acc)
// Input projection depends only on vocab id -> precompute once for all ids.
// grid 500 x 512thr; block covers 64 vocab; 8 waves = 4 v-tiles x 2 h-halves.
// ---------------------------------------------------------------------------
__global__ __launch_bounds__(512, 1) void k0_pp(
    const float* __restrict__ emb, const float* __restrict__ Wih,
    const float* __restrict__ bih, const float* __restrict__ bhh,
    __bf16* __restrict__ pp)
{
    const int tid = threadIdx.x;
    const int lane = tid & 63, w = tid >> 6;
    const int nt = w >> 1;               // vocab tile 0..3
    const int mh = w & 1;                // h half 0..1 (4 m-tiles each)
    const int v0 = blockIdx.x * 64;
    const int sub = lane >> 4, rc = lane & 15;
    const f32x4 z = {0.f, 0.f, 0.f, 0.f};

    bf16x8 af[4][4];
#pragma unroll
    for (int m = 0; m < 4; ++m)
#pragma unroll
        for (int kc = 0; kc < 4; ++kc) {
            int row = (mh * 4 + m) * 16 + rc;
            int k0 = kc * 32 + sub * 8;
            const float* s = Wih + (size_t)row * E_ + k0;
            f32x4 p0 = (k0 + 4 <= E_) ? *(const f32x4*)s : z;
            f32x4 p1 = (k0 + 8 <= E_) ? *(const f32x4*)(s + 4) : z;
            bf16x8 h8;
#pragma unroll
            for (int e = 0; e < 4; ++e) {
                h8[e] = (__bf16)p0[e];
                h8[4 + e] = (__bf16)p1[e];
            }
            af[m][kc] = h8;
        }

    bf16x8 bf[4];
#pragma unroll
    for (int kc = 0; kc < 4; ++kc) {
        int vrow = v0 + nt * 16 + rc;
        int k0 = kc * 32 + sub * 8;
        const float* s = emb + (size_t)vrow * E_ + k0;
        f32x4 p0 = (k0 + 4 <= E_) ? *(const f32x4*)s : z;
        f32x4 p1 = (k0 + 8 <= E_) ? *(const f32x4*)(s + 4) : z;
        bf16x8 h8;
#pragma unroll
        for (int e = 0; e < 4; ++e) {
            h8[e] = (__bf16)p0[e];
            h8[4 + e] = (__bf16)p1[e];
        }
        bf[kc] = h8;
    }

    f32x4 acc[4];
#pragma unroll
    for (int m = 0; m < 4; ++m) {
        int h0 = (mh * 4 + m) * 16 + sub * 4;
        acc[m] = *(const f32x4*)&bih[h0] + *(const f32x4*)&bhh[h0];
    }
#pragma unroll
    for (int kc = 0; kc < 4; ++kc)
#pragma unroll
        for (int m = 0; m < 4; ++m)
            acc[m] = mfma16(af[m][kc], bf[kc], acc[m]);

#pragma unroll
    for (int m = 0; m < 4; ++m) {
        int v = v0 + nt * 16 + rc;
        int h0 = (mh * 4 + m) * 16 + sub * 4;
        bf16x4 o;
#pragma unroll
        for (int r = 0; r < 4; ++r) o[r] = (__bf16)acc[m][r];
        *(bf16x4*)&pp[(size_t)v * H_ + h0] = o;
    }
}

// ---------------------------------------------------------------------------
// K2: RNN scan. 64 blocks x 16 batch; 8 waves (2/SIMD); wave w owns hidden
// rows [16w,16w+16). xt from pp[x[b,t]] gathers, STAGGERED one-per-step
// (issued in step t for step t+4; sched_barrier(0) pins them per-step, so no
// group-top VMEM burst). Indices i32x4 loaded in step 3 of each group,
// pointer clamped at the tail. Position-named regs (counted vmcnt). Static
// LDS ping-pong; xt folded into MFMA C-init; 1 barrier/step.
// ---------------------------------------------------------------------------
__global__ __launch_bounds__(512, 1) void k2_rnn(
    const int* __restrict__ x, const __bf16* __restrict__ pp,
    const float* __restrict__ Whh, __bf16* __restrict__ hg)
{
    __shared__ __align__(16) __bf16 Hg[2][2048];
    const int tid = threadIdx.x;
    const int lane = tid & 63, w = tid >> 6;
    const int bi = blockIdx.x;
    const int b0 = bi * 16;
    const int sub = lane >> 4, c = lane & 15;

    // A fragments: W_hh rows w*16 + c (bf16); loop-invariant
    bf16x8 wah[4];
#pragma unroll
    for (int kc = 0; kc < 4; ++kc) {
        const float* src = Whh + (size_t)(w * 16 + c) * H_ + kc * 32 + sub * 8;
        f32x4 p0 = *(const f32x4*)src, p1 = *(const f32x4*)(src + 4);
        bf16x8 h8;
#pragma unroll
        for (int e = 0; e < 4; ++e) {
            h8[e] = (__bf16)p0[e];
            h8[4 + e] = (__bf16)p1[e];
        }
        wah[kc] = h8;
    }

    if (tid < 256) {
        bf16x8 z8;
#pragma unroll
        for (int e = 0; e < 8; ++e) z8[e] = (__bf16)0.0f;
        *(bf16x8*)&Hg[0][tid * 8] = z8;
    }
    __syncthreads();

    const int i0 = w * 16 + sub * 4;            // this lane's 4 hidden-out rows
    const int* xrow = x + (size_t)(b0 + c) * T_; // this lane's batch index row
    const __bf16* ppi = pp + i0;

    // LDS write elem-offset for hidden rows i0..i0+3, col c (granule layout)
    const int wb = (((w >> 1) * 64 + ((w & 1) * 2 + (sub >> 1)) * 16 + c) << 3)
                 + (sub & 1) * 4;

    bf16x4 h4;                                   // last-written h (for hg)

    // GBODY: one gather / index-load, placed after MFMA issue within the step
#define K2_STEP(PK, XREG, GBODY) do {                                       \
        const __bf16* Hp = &Hg[PK][0];                                      \
        bf16x8 hb0 = *(const bf16x8*)(Hp + lane * 8);                       \
        bf16x8 hb1 = *(const bf16x8*)(Hp + 512 + lane * 8);                 \
        bf16x8 hb2 = *(const bf16x8*)(Hp + 1024 + lane * 8);                \
        bf16x8 hb3 = *(const bf16x8*)(Hp + 1536 + lane * 8);                \
        f32x4 xf;                                                           \
        _Pragma("unroll")                                                   \
        for (int r = 0; r < 4; ++r) xf[r] = (float)XREG[r];                 \
        f32x4 zz = {0.f, 0.f, 0.f, 0.f};                                    \
        f32x4 a0 = mfma16(wah[0], hb0, xf);                                 \
        f32x4 a1 = mfma16(wah[1], hb1, zz);                                 \
        a0 = mfma16(wah[2], hb2, a0);                                       \
        a1 = mfma16(wah[3], hb3, a1);                                       \
        GBODY;                                                              \
        f32x4 s = a0 + a1;                                                  \
        _Pragma("unroll")                                                   \
        for (int r = 0; r < 4; ++r) {                                       \
            float e;                                                        \
            asm("v_exp_f32 %0, %1" : "=v"(e) : "v"(s[r] * 2.8853900817779268f)); \
            float ep1 = e + 1.0f;                                           \
            float rcp;                                                      \
            asm("v_rcp_f32 %0, %1" : "=v"(rcp) : "v"(ep1));                 \
            h4[r] = (__bf16)(1.0f - 2.0f * rcp);                            \
        }                                                                   \
        *(bf16x4*)&Hg[(PK) ^ 1][wb] = h4;                                   \
        asm volatile("s_waitcnt lgkmcnt(0)" ::: "memory");                  \
        __builtin_amdgcn_s_barrier();                                       \
        __builtin_amdgcn_sched_barrier(0);                                  \
    } while (0)

    // prologue: indices + gathers for steps 0..3; indices for steps 4..7
    i32x4 xs0 = *(const i32x4*)(xrow);
    bf16x4 xc0 = *(const bf16x4*)(ppi + (size_t)xs0[0] * H_);
    bf16x4 xc1 = *(const bf16x4*)(ppi + (size_t)xs0[1] * H_);
    bf16x4 xc2 = *(const bf16x4*)(ppi + (size_t)xs0[2] * H_);
    bf16x4 xc3 = *(const bf16x4*)(ppi + (size_t)xs0[3] * H_);
    i32x4 xsA = *(const i32x4*)(xrow + 4);

    for (int j = 0; j < T_ / 4; ++j) {
        bf16x4 xn0, xn1, xn2, xn3;
        i32x4 xsB;
        // clamped pointers: tail groups read valid (unused) data
        int tg = 4 * (j + 2);
        const int* xnext = xrow + (tg <= T_ - 4 ? tg : T_ - 4);

        K2_STEP(0, xc0, { xn0 = *(const bf16x4*)(ppi + (size_t)xsA[0] * H_); });
        K2_STEP(1, xc1, { xn1 = *(const bf16x4*)(ppi + (size_t)xsA[1] * H_); });
        K2_STEP(0, xc2, { xn2 = *(const bf16x4*)(ppi + (size_t)xsA[2] * H_); });
        K2_STEP(1, xc3, { xn3 = *(const bf16x4*)(ppi + (size_t)xsA[3] * H_);
                          xsB = *(const i32x4*)(xnext); });

        xc0 = xn0; xc1 = xn1; xc2 = xn2; xc3 = xn3;
        xsA = xsB;
    }
#undef K2_STEP

    // final h of step T-1 -> hg granules for K3
    *(bf16x4*)&hg[(size_t)(bi >> 3) * 16384 + (size_t)(bi & 7) * 2048 + wb] = h4;
}

// ---------------------------------------------------------------------------
// K3: out[b][v] = h[b] @ W_fc[v]^T + b_fc[v]. One block per v-tile (gv);
// A-frags cvt'd from f32 Wfc ONCE, loop over all 8 batch-tiles. grid 250.
// ---------------------------------------------------------------------------
__global__ __launch_bounds__(512, 1) void k3_head(
    const float* __restrict__ Wfc, const __bf16* __restrict__ hg,
    const float* __restrict__ bfc, float* __restrict__ out)
{
    const int tid = threadIdx.x;
    const int lane = tid & 63, w = tid >> 6;
    const int gv = blockIdx.x;
    const int v0 = gv * 128;
    const int sub = lane >> 4, rc = lane & 15;
    const int mt0 = (w & 3) * 2, nt0 = (w >> 2) * 4;

    bf16x8 af[2][4];
#pragma unroll
    for (int m = 0; m < 2; ++m)
#pragma unroll
        for (int kc = 0; kc < 4; ++kc) {
            int row = v0 + (mt0 + m) * 16 + rc;
            const float* src = Wfc + (size_t)row * H_ + (kc * 4 + sub) * 8;
            f32x4 p0 = *(const f32x4*)src, p1 = *(const f32x4*)(src + 4);
            bf16x8 h8;
#pragma unroll
            for (int e = 0; e < 4; ++e) {
                h8[e] = (__bf16)p0[e];
                h8[4 + e] = (__bf16)p1[e];
            }
            af[m][kc] = h8;
        }

    f32x4 bias4[2];
#pragma unroll
    for (int m = 0; m < 2; ++m)
        bias4[m] = *(const f32x4*)&bfc[v0 + (mt0 + m) * 16 + sub * 4];

    for (int bt = 0; bt < 8; ++bt) {
        const int b0 = bt * 128;
        f32x4 acc[2][4];
#pragma unroll
        for (int m = 0; m < 2; ++m)
#pragma unroll
            for (int n = 0; n < 4; ++n) acc[m][n] = (f32x4){0.f, 0.f, 0.f, 0.f};

#pragma unroll
        for (int kc = 0; kc < 4; ++kc) {
            bf16x8 bf[4];
#pragma unroll
            for (int n = 0; n < 4; ++n)
                bf[n] = *(const bf16x8*)&hg[(size_t)bt * 16384
                          + (size_t)(((nt0 + n) * 256) + kc * 64 + lane) * 8];
#pragma unroll
            for (int n = 0; n < 4; ++n)
#pragma unroll
                for (int m = 0; m < 2; ++m)
                    acc[m][n] = mfma16(af[m][kc], bf[n], acc[m][n]);
        }
#pragma unroll
        for (int n = 0; n < 4; ++n)
#pragma unroll
            for (int m = 0; m < 2; ++m) {
                f32x4 v = acc[m][n] + bias4[m];
                float* dst = out + (size_t)(b0 + (nt0 + n) * 16 + rc) * V_
                                 + v0 + (mt0 + m) * 16 + sub * 4;
                *(f32x4*)dst = v;
            }
    }
}

extern "C" void kernel_launch(void* const* d_in, const int* in_sizes, int n_in,
                              void* d_out, int out_size, void* d_ws, size_t ws_size,
                              hipStream_t stream) {
    const int*   x   = (const int*)d_in[0];
    const float* emb = (const float*)d_in[1];
    const float* Wih = (const float*)d_in[2];
    const float* Whh = (const float*)d_in[3];
    const float* bih = (const float*)d_in[4];
    const float* bhh = (const float*)d_in[5];
    const float* Wfc = (const float*)d_in[6];
    const float* bfc = (const float*)d_in[7];
    float* out = (float*)d_out;

    const size_t SZ_HG = 262144;                    // 8 x 16384 bf16
    const size_t SZ_PP = (size_t)V_ * H_ * 2;       // 8.192 MB

    char* wsb = (char*)d_ws;
    size_t off = 0;
    auto take = [&](size_t n) -> char* {
        char* p = wsb + off;
        off += (n + 255) & ~(size_t)255;
        return p;
    };
    auto fits = [&](size_t n) { return off + n + 256 <= ws_size; };

    __bf16* hgp = (__bf16*)take(SZ_HG);             // required in ws
    // pp: prefer ws; fallback into d_out (k3 overwrites it only after k2 done)
    __bf16* pp = fits(SZ_PP) ? (__bf16*)take(SZ_PP) : (__bf16*)d_out;

    k0_pp<<<dim3(500), 512, 0, stream>>>(emb, Wih, bih, bhh, pp);
    k2_rnn<<<dim3(64), 512, 0, stream>>>(x, pp, Whh, hgp);
    k3_head<<<dim3(250), 512, 0, stream>>>(Wfc, hgp, bfc, out);
}